// Round 18
// baseline (862.453 us; speedup 1.0000x reference)
//
#include <hip/hip_runtime.h>
#include <hip/hip_bf16.h>

typedef __bf16 bf16;
typedef __attribute__((ext_vector_type(8))) __bf16 bf16x8;
typedef __attribute__((ext_vector_type(4))) __bf16 bf16x4;
typedef __attribute__((ext_vector_type(4))) float f32x4;
typedef __attribute__((ext_vector_type(4))) int i32x4;
typedef __attribute__((ext_vector_type(4))) short s16x4;
typedef unsigned long long u64;

constexpr int SLEN = 2048;
constexpr int DH = 64;
constexpr int NBH = 64;                      // B*H = 4*16
constexpr int NT = SLEN / 64;                // 32 k-tiles
constexpr float SCALE_LOG2E = 0.125f * 1.4426950408889634f;  // (1/sqrt(64)) * log2(e)

// ---- fused pre-pass: K fp32->bf16 (coalesced) + V fp32 [s][d] -> bf16 Vt [d][s] ----
__global__ __launch_bounds__(256) void prep_kv_kernel(
    const float* __restrict__ K, const float* __restrict__ V,
    bf16* __restrict__ Kb, bf16* __restrict__ Vt)
{
    __shared__ float t[64][65];
    const int bh = blockIdx.y;
    const int s0 = blockIdx.x * 64;
    const int tx = threadIdx.x & 63, ty = threadIdx.x >> 6;

    // V tile -> LDS
    const float* vp = V + ((size_t)bh * SLEN + s0) * DH;
    #pragma unroll
    for (int r = ty; r < 64; r += 4) t[r][tx] = vp[(size_t)r * DH + tx];

    // K cast (independent of LDS; overlaps the transpose latency)
    {
        const float* kp = K + ((size_t)bh * SLEN + s0) * DH;
        bf16* kbp = Kb + ((size_t)bh * SLEN + s0) * DH;
        int r = threadIdx.x >> 2, c = (threadIdx.x & 3) * 16;
        const float4* src = (const float4*)(kp + (size_t)r * DH + c);
        float4 a = src[0], b = src[1], c2 = src[2], d = src[3];
        bf16x8 o0, o1;
        o0[0]=(bf16)a.x;  o0[1]=(bf16)a.y;  o0[2]=(bf16)a.z;  o0[3]=(bf16)a.w;
        o0[4]=(bf16)b.x;  o0[5]=(bf16)b.y;  o0[6]=(bf16)b.z;  o0[7]=(bf16)b.w;
        o1[0]=(bf16)c2.x; o1[1]=(bf16)c2.y; o1[2]=(bf16)c2.z; o1[3]=(bf16)c2.w;
        o1[4]=(bf16)d.x;  o1[5]=(bf16)d.y;  o1[6]=(bf16)d.z;  o1[7]=(bf16)d.w;
        *(bf16x8*)(kbp + (size_t)r * DH + c)     = o0;
        *(bf16x8*)(kbp + (size_t)r * DH + c + 8) = o1;
    }

    __syncthreads();
    bf16* op = Vt + (size_t)bh * DH * SLEN + s0;
    #pragma unroll
    for (int r = ty; r < 64; r += 4) op[(size_t)r * SLEN + tx] = (bf16)t[tx][r];
}

// async global->LDS, 16B per lane, dest = wave-uniform base + lane*16
__device__ __forceinline__ void gl_lds16(const void* g, void* l) {
    __builtin_amdgcn_global_load_lds(
        (const __attribute__((address_space(1))) void*)g,
        (__attribute__((address_space(3))) void*)l, 16, 0, 0);
}

// 16x16x16 bf16 MFMA (instruction exists on gfx950: cdna4_isa §10).
__device__ __forceinline__ f32x4 pv_mfma(bf16x4 a, bf16x4 b, f32x4 c) {
#if __has_builtin(__builtin_amdgcn_mfma_f32_16x16x16bf16_1k)
    return __builtin_amdgcn_mfma_f32_16x16x16bf16_1k(
        __builtin_bit_cast(s16x4, a), __builtin_bit_cast(s16x4, b), c, 0, 0, 0);
#else
    f32x4 d;
    asm("s_nop 1\n\t"
        "v_mfma_f32_16x16x16_bf16 %0, %1, %2, %3\n\t"
        "s_nop 7"
        : "=v"(d) : "v"(a), "v"(b), "v"(c));
    return d;
#endif
}

// ---- main attention kernel ----
// vs R17 (single variable): 2-DEEP mask pipeline. Masks for tile t are
// loaded at round t-2 into the named buffer rawA/rawB (t even/odd; loop 2x
// unrolled so all indexing is static — rule #20). Steady state at round kt's
// tile_sync: outstanding = masks(kt+1) + 4 gl_lds + masks(kt+2); vmcnt(4)
// retires masks(kt+1)+gl_lds, leaves masks(kt+2) flying. So extract at round
// kt+1 NEVER waits — the mask wait collapses into the barrier one round
// early, with ~2 rounds (~4500cyc) of latency slack vs ~1200cyc before.
// Everything else identical to R17: wave-contiguous mask loads + ballot
// redistribute, 4 waves / 64 q-rows / 32KB LDS / (256,5) -> 5 blocks/CU,
// counted-vmcnt schedule, K/V source-side XOR swizzle, XCD-bijective block
// swizzle, register-P PV via 16x16x16 MFMA.
// masked_fill is 0 (not -inf), |s|<=~7 -> unnormalized exp safe; one divide.
__global__ __launch_bounds__(256, 5) void attn_kernel(
    const float* __restrict__ Q, const int* __restrict__ mask,
    const bf16* __restrict__ Kb, const bf16* __restrict__ Vtb,
    float* __restrict__ out)
{
    __shared__ char KT[2][8192];
    __shared__ char VT[2][8192];

    // XCD-aware bijective swizzle (2048 blocks, 2048%8==0): XCD x owns bh 8x..8x+7
    const int h = blockIdx.x;
    const int logical = (h & 7) * 256 + (h >> 3);
    const int bh = logical >> 5;
    const int qbase = (logical & 31) * 64;
    const int tid = threadIdx.x;
    const int w = tid >> 6, l = tid & 63;
    const int lq = l & 15, lg = l >> 4;

    const char* kgb = (const char*)(Kb + (size_t)bh * SLEN * DH);      // rows 128B
    const char* vgb = (const char*)(Vtb + (size_t)bh * DH * SLEN);     // rows 4096B

    // staging geometry: lane covers (row octet kv_r, swizzled 16B col kv_c)
    const int kv_r = l >> 3;                             // 0..7
    const int kv_c = ((l & 7) * 16) ^ (kv_r << 4);

    // Q B-frags (q-col = lq, k = t*32+lg*8+j), hoisted fp32->bf16
    bf16x8 aq[2];
    {
        const float* qp = Q + ((size_t)bh * SLEN + qbase + w * 16 + lq) * DH + lg * 8;
        #pragma unroll
        for (int t = 0; t < 2; ++t) {
            float4 x = *(const float4*)(qp + t * 32);
            float4 y = *(const float4*)(qp + t * 32 + 4);
            bf16x8 f;
            f[0]=(bf16)x.x; f[1]=(bf16)x.y; f[2]=(bf16)x.z; f[3]=(bf16)x.w;
            f[4]=(bf16)y.x; f[5]=(bf16)y.y; f[6]=(bf16)y.z; f[7]=(bf16)y.w;
            aq[t] = f;
        }
    }

    f32x4 acc[4] = {{0,0,0,0},{0,0,0,0},{0,0,0,0},{0,0,0,0}};
    float dpart = 0.f;
    const int swzk = (lq & 7) << 4;      // read-side XOR, row%8 == lq%8

    // contiguous mask base: lane l covers row-in-quartet (l>>4), ints (l&15)*4
    const int* mrowc = mask + ((size_t)bh * SLEN + qbase + w * 16 + (l >> 4)) * SLEN
                            + (l & 15) * 4;

    // K/V staging for k-tile index t: 4 gl_lds per wave (2 K + 2 V)
    auto stage = [&](int t, int buf) {
        const int kb = t * 64;                           // element offset
        #pragma unroll
        for (int q = 0; q < 2; ++q) {
            int r = (w * 2 + q) * 8 + kv_r;              // tile row 0..63
            gl_lds16(kgb + (size_t)(kb + r) * 128 + kv_c, &KT[buf][(w * 2 + q) * 1024]);
            gl_lds16(vgb + (size_t)r * 4096 + (size_t)kb * 2 + kv_c, &VT[buf][(w * 2 + q) * 1024]);
        }
    };
    // wave-contiguous mask loads: instruction j = rows qbase+w*16+j*4..+3,
    // 1KB contiguous per wave (4 x 256B row-segments)
    auto loadmask = [&](int t, i32x4* m) {
        #pragma unroll
        for (int j = 0; j < 4; ++j)
            m[j] = __builtin_nontemporal_load(
                (const i32x4*)(mrowc + (size_t)j * 4 * SLEN + t * 64));
    };
    // ballot-redistribute raw -> pmall; bit (n*4+i) = mask(row lq, col n*16+lg*4+i)
    const int jsel = lq >> 2;
    const int shb = (lq & 3) * 16 + lg;
    auto extract = [&](const i32x4* m) -> unsigned {
        unsigned pmall = 0;
        #pragma unroll
        for (int i = 0; i < 4; ++i) {
            u64 b0 = __ballot(m[0][i] != 0);
            u64 b1 = __ballot(m[1][i] != 0);
            u64 b2 = __ballot(m[2][i] != 0);
            u64 b3 = __ballot(m[3][i] != 0);
            u64 b = jsel == 0 ? b0 : jsel == 1 ? b1 : jsel == 2 ? b2 : b3;
            unsigned lo = (unsigned)(b >> shb) & 0x1111u;  // bits n*4, n=0..3
            pmall |= lo << i;
        }
        return pmall;
    };
    // one k-tile of compute: LDS buf `cur`, packed mask bits pmall
    auto body = [&](int cur, unsigned pmall) {
        bf16x4 p[4];
        #pragma unroll
        for (int n = 0; n < 4; ++n) {
            f32x4 s = {0, 0, 0, 0};
            #pragma unroll
            for (int t = 0; t < 2; ++t) {
                bf16x8 bk = *(const bf16x8*)&KT[cur][(n * 16 + lq) * 128 + ((t * 64 + lg * 16) ^ swzk)];
                s = __builtin_amdgcn_mfma_f32_16x16x32_bf16(bk, aq[t], s, 0, 0, 0);
            }
            #pragma unroll
            for (int i = 0; i < 4; ++i) {
                float pe = exp2f(s[i] * SCALE_LOG2E);
                pe = ((pmall >> (n * 4 + i)) & 1u) ? 1.0f : pe;  // masked -> weight 1
                dpart += pe;
                p[n][i] = (bf16)pe;
            }
        }
        #pragma unroll
        for (int nn = 0; nn < 4; ++nn) {
            #pragma unroll
            for (int n = 0; n < 4; ++n) {
                bf16x4 bv = *(const bf16x4*)&VT[cur][(nn * 16 + lq) * 128 + ((n * 32 + lg * 8) ^ swzk)];
                acc[nn] = pv_mfma(p[n], bv, acc[nn]);
            }
        }
    };
    // counted sync: retires masks(t+1)+gl_lds; masks(t+2) (4 newest) fly on.
    auto tile_sync = [&]() {
        asm volatile("s_waitcnt vmcnt(4) lgkmcnt(0)" ::: "memory");
        __builtin_amdgcn_s_barrier();
        __builtin_amdgcn_sched_barrier(0);
    };

    i32x4 rawA[4], rawB[4];   // mask buffers: rawA = even tiles, rawB = odd

    // prologue: tile 0 -> buf0; masks(0) -> rawA, masks(1) -> rawB.
    // vmcnt(4) at sync retires gl_lds + masks(0); masks(1) stay in flight.
    stage(0, 0);
    __builtin_amdgcn_sched_barrier(0);
    loadmask(0, rawA);
    loadmask(1, rawB);
    tile_sync();

    for (int kt = 0; kt < NT; kt += 2) {
        // even tile kt: compute from buf0/rawA; prefetch stage(kt+1)->buf1,
        // masks(kt+2)->rawA
        {
            const bool m2 = (kt + 2) < NT;
            stage(kt + 1, 1);
            __builtin_amdgcn_sched_barrier(0);
            unsigned pmall = extract(rawA);
            if (m2) loadmask(kt + 2, rawA);
            __builtin_amdgcn_sched_barrier(0);
            body(0, pmall);
            tile_sync();
        }
        // odd tile kt+1: compute from buf1/rawB; prefetch stage(kt+2)->buf0,
        // masks(kt+3)->rawB
        {
            const bool m2 = (kt + 2) < NT;
            const bool m3 = (kt + 3) < NT;
            if (m2) stage(kt + 2, 0);
            __builtin_amdgcn_sched_barrier(0);
            unsigned pmall = extract(rawB);
            if (m3) loadmask(kt + 3, rawB);
            __builtin_amdgcn_sched_barrier(0);
            body(1, pmall);
            if (m2) tile_sync();
        }
    }

    // denom: lanes {lq, lq+16, lq+32, lq+48} hold partials for q-row lq
    dpart += __shfl_xor(dpart, 16, 64);
    dpart += __shfl_xor(dpart, 32, 64);
    float dinv = 1.0f / dpart;

    float di[4];
    #pragma unroll
    for (int i = 0; i < 4; ++i) di[i] = __shfl(dinv, lg * 4 + i, 64);

    float* op = out + ((size_t)bh * SLEN + qbase + w * 16) * DH;
    #pragma unroll
    for (int n = 0; n < 4; ++n) {
        #pragma unroll
        for (int i = 0; i < 4; ++i)
            op[(size_t)(lg * 4 + i) * DH + n * 16 + lq] = acc[n][i] * di[i];
    }
}

extern "C" void kernel_launch(void* const* d_in, const int* in_sizes, int n_in,
                              void* d_out, int out_size, void* d_ws, size_t ws_size,
                              hipStream_t stream) {
    const float* Q    = (const float*)d_in[0];
    const float* K    = (const float*)d_in[1];
    const float* V    = (const float*)d_in[2];
    const int*   mask = (const int*)d_in[3];
    float* out = (float*)d_out;

    bf16* Kb  = (bf16*)d_ws;                       // 16 MB
    bf16* Vtb = Kb + (size_t)NBH * SLEN * DH;      // 16 MB

    prep_kv_kernel<<<dim3(SLEN / 64, NBH), 256, 0, stream>>>(K, V, Kb, Vtb);
    attn_kernel<<<2048, 256, 0, stream>>>(Q, mask, Kb, Vtb, out);
}

// Round 19
// 300.843 us; speedup vs baseline: 2.8668x; 2.8668x over previous
//
#include <hip/hip_runtime.h>
#include <hip/hip_bf16.h>

typedef __bf16 bf16;
typedef __attribute__((ext_vector_type(8))) __bf16 bf16x8;
typedef __attribute__((ext_vector_type(4))) __bf16 bf16x4;
typedef __attribute__((ext_vector_type(4))) float f32x4;
typedef __attribute__((ext_vector_type(4))) int i32x4;
typedef __attribute__((ext_vector_type(4))) short s16x4;
typedef unsigned long long u64;

constexpr int SLEN = 2048;
constexpr int DH = 64;
constexpr int NBH = 64;                      // B*H = 4*16
constexpr int NT = SLEN / 64;                // 32 k-tiles
constexpr float SCALE_LOG2E = 0.125f * 1.4426950408889634f;  // (1/sqrt(64)) * log2(e)

// ---- fused pre-pass: K fp32->bf16 (coalesced) + V fp32 [s][d] -> bf16 Vt [d][s] ----
__global__ __launch_bounds__(256) void prep_kv_kernel(
    const float* __restrict__ K, const float* __restrict__ V,
    bf16* __restrict__ Kb, bf16* __restrict__ Vt)
{
    __shared__ float t[64][65];
    const int bh = blockIdx.y;
    const int s0 = blockIdx.x * 64;
    const int tx = threadIdx.x & 63, ty = threadIdx.x >> 6;

    // V tile -> LDS
    const float* vp = V + ((size_t)bh * SLEN + s0) * DH;
    #pragma unroll
    for (int r = ty; r < 64; r += 4) t[r][tx] = vp[(size_t)r * DH + tx];

    // K cast (independent of LDS; overlaps the transpose latency)
    {
        const float* kp = K + ((size_t)bh * SLEN + s0) * DH;
        bf16* kbp = Kb + ((size_t)bh * SLEN + s0) * DH;
        int r = threadIdx.x >> 2, c = (threadIdx.x & 3) * 16;
        const float4* src = (const float4*)(kp + (size_t)r * DH + c);
        float4 a = src[0], b = src[1], c2 = src[2], d = src[3];
        bf16x8 o0, o1;
        o0[0]=(bf16)a.x;  o0[1]=(bf16)a.y;  o0[2]=(bf16)a.z;  o0[3]=(bf16)a.w;
        o0[4]=(bf16)b.x;  o0[5]=(bf16)b.y;  o0[6]=(bf16)b.z;  o0[7]=(bf16)b.w;
        o1[0]=(bf16)c2.x; o1[1]=(bf16)c2.y; o1[2]=(bf16)c2.z; o1[3]=(bf16)c2.w;
        o1[4]=(bf16)d.x;  o1[5]=(bf16)d.y;  o1[6]=(bf16)d.z;  o1[7]=(bf16)d.w;
        *(bf16x8*)(kbp + (size_t)r * DH + c)     = o0;
        *(bf16x8*)(kbp + (size_t)r * DH + c + 8) = o1;
    }

    __syncthreads();
    bf16* op = Vt + (size_t)bh * DH * SLEN + s0;
    #pragma unroll
    for (int r = ty; r < 64; r += 4) op[(size_t)r * SLEN + tx] = (bf16)t[tx][r];
}

// async global->LDS, 16B per lane, dest = wave-uniform base + lane*16
__device__ __forceinline__ void gl_lds16(const void* g, void* l) {
    __builtin_amdgcn_global_load_lds(
        (const __attribute__((address_space(1))) void*)g,
        (__attribute__((address_space(3))) void*)l, 16, 0, 0);
}

// 16x16x16 bf16 MFMA (instruction exists on gfx950: cdna4_isa §10).
__device__ __forceinline__ f32x4 pv_mfma(bf16x4 a, bf16x4 b, f32x4 c) {
#if __has_builtin(__builtin_amdgcn_mfma_f32_16x16x16bf16_1k)
    return __builtin_amdgcn_mfma_f32_16x16x16bf16_1k(
        __builtin_bit_cast(s16x4, a), __builtin_bit_cast(s16x4, b), c, 0, 0, 0);
#else
    f32x4 d;
    asm("s_nop 1\n\t"
        "v_mfma_f32_16x16x16_bf16 %0, %1, %2, %3\n\t"
        "s_nop 7"
        : "=v"(d) : "v"(a), "v"(b), "v"(c));
    return d;
#endif
}

// ---- main attention kernel (R17 verbatim — best measured: 300.7us) ----
// 4 waves, 64 q-rows/block, 32KB LDS (KT+VT dbuf), (256,5) -> 5 blocks/CU.
// Wave-contiguous mask loads (4 x 256B segments per instruction) + ballot
// redistribute: bit l' of ballot(raw_j[i]!=0) = mask(row j*4+(l'>>4), col
// (l'&15)*4+i); lane (lq,lg) extracts bit (lq&3)*16+n*4+lg of ballot j=lq>>2.
// Single raw[4] buffer, 1-tile-ahead (2-deep variant R18 spilled: VGPR cap
// at 5 blocks/CU cannot hold a second buffer — WRITE_SIZE 2.1GB, 862us).
// Counted-vmcnt schedule: per tile {4 gl_lds, extract, 4 mask loads};
// sync = s_waitcnt vmcnt(4) lgkmcnt(0) + s_barrier (masks fly through).
// K/V LDS rows swizzled byte^=(row&7)<<4 on the GLOBAL SOURCE side, mirrored
// on reads. XCD-bijective block swizzle: XCD x owns bh 8x..8x+7.
// Swapped QK^T: lane (lq,lg) holds scores for q-row lq, k=n*16+lg*4+i; PV
// consumes P from registers via 16x16x16 MFMA (V B-frag = b64 LDS read).
// masked_fill is 0 (not -inf), |s|<=~7 -> unnormalized exp safe; one divide.
// Falsified levers (do not revisit): 128-row tile (R13-15: spill/occupancy),
// mask pre-packing (R3), P-LDS round-trip removal (neutral), 2-deep mask
// pipeline (R18: spill at (256,5)).
__global__ __launch_bounds__(256, 5) void attn_kernel(
    const float* __restrict__ Q, const int* __restrict__ mask,
    const bf16* __restrict__ Kb, const bf16* __restrict__ Vtb,
    float* __restrict__ out)
{
    __shared__ char KT[2][8192];
    __shared__ char VT[2][8192];

    // XCD-aware bijective swizzle (2048 blocks, 2048%8==0): XCD x owns bh 8x..8x+7
    const int h = blockIdx.x;
    const int logical = (h & 7) * 256 + (h >> 3);
    const int bh = logical >> 5;
    const int qbase = (logical & 31) * 64;
    const int tid = threadIdx.x;
    const int w = tid >> 6, l = tid & 63;
    const int lq = l & 15, lg = l >> 4;

    const char* kgb = (const char*)(Kb + (size_t)bh * SLEN * DH);      // rows 128B
    const char* vgb = (const char*)(Vtb + (size_t)bh * DH * SLEN);     // rows 4096B

    // staging geometry: lane covers (row octet kv_r, swizzled 16B col kv_c)
    const int kv_r = l >> 3;                             // 0..7
    const int kv_c = ((l & 7) * 16) ^ (kv_r << 4);

    // Q B-frags (q-col = lq, k = t*32+lg*8+j), hoisted fp32->bf16
    bf16x8 aq[2];
    {
        const float* qp = Q + ((size_t)bh * SLEN + qbase + w * 16 + lq) * DH + lg * 8;
        #pragma unroll
        for (int t = 0; t < 2; ++t) {
            float4 x = *(const float4*)(qp + t * 32);
            float4 y = *(const float4*)(qp + t * 32 + 4);
            bf16x8 f;
            f[0]=(bf16)x.x; f[1]=(bf16)x.y; f[2]=(bf16)x.z; f[3]=(bf16)x.w;
            f[4]=(bf16)y.x; f[5]=(bf16)y.y; f[6]=(bf16)y.z; f[7]=(bf16)y.w;
            aq[t] = f;
        }
    }

    f32x4 acc[4] = {{0,0,0,0},{0,0,0,0},{0,0,0,0},{0,0,0,0}};
    float dpart = 0.f;
    const int swzk = (lq & 7) << 4;      // read-side XOR, row%8 == lq%8

    // contiguous mask base: lane l covers row-in-quartet (l>>4), ints (l&15)*4
    const int* mrowc = mask + ((size_t)bh * SLEN + qbase + w * 16 + (l >> 4)) * SLEN
                            + (l & 15) * 4;

    // K/V staging for k-tile index t: 4 gl_lds per wave (2 K + 2 V)
    auto stage = [&](int t, int buf) {
        const int kb = t * 64;                           // element offset
        #pragma unroll
        for (int q = 0; q < 2; ++q) {
            int r = (w * 2 + q) * 8 + kv_r;              // tile row 0..63
            gl_lds16(kgb + (size_t)(kb + r) * 128 + kv_c, &KT[buf][(w * 2 + q) * 1024]);
            gl_lds16(vgb + (size_t)r * 4096 + (size_t)kb * 2 + kv_c, &VT[buf][(w * 2 + q) * 1024]);
        }
    };
    // wave-contiguous mask loads: instruction j = rows qbase+w*16+j*4..+3,
    // 1KB contiguous per wave (4 x 256B row-segments)
    auto loadmask = [&](int t, i32x4* m) {
        #pragma unroll
        for (int j = 0; j < 4; ++j)
            m[j] = __builtin_nontemporal_load(
                (const i32x4*)(mrowc + (size_t)j * 4 * SLEN + t * 64));
    };
    // ballot-redistribute raw (this tile's masks, loaded last round) -> pmall
    // pmall bit (n*4+i) = mask(row lq, col n*16+lg*4+i) != 0
    const int jsel = lq >> 2;
    const int shb = (lq & 3) * 16 + lg;
    auto extract = [&](const i32x4* m) -> unsigned {
        unsigned pmall = 0;
        #pragma unroll
        for (int i = 0; i < 4; ++i) {
            u64 b0 = __ballot(m[0][i] != 0);
            u64 b1 = __ballot(m[1][i] != 0);
            u64 b2 = __ballot(m[2][i] != 0);
            u64 b3 = __ballot(m[3][i] != 0);
            u64 b = jsel == 0 ? b0 : jsel == 1 ? b1 : jsel == 2 ? b2 : b3;
            unsigned lo = (unsigned)(b >> shb) & 0x1111u;  // bits n*4, n=0..3
            pmall |= lo << i;
        }
        return pmall;
    };
    // one k-tile of compute: LDS buf `cur`, packed mask bits pmall
    auto body = [&](int cur, unsigned pmall) {
        // QK^T: S^T subtile n -> p[n] (bf16x4, q=lq, k=n*16+lg*4+i)
        bf16x4 p[4];
        #pragma unroll
        for (int n = 0; n < 4; ++n) {
            f32x4 s = {0, 0, 0, 0};
            #pragma unroll
            for (int t = 0; t < 2; ++t) {
                bf16x8 bk = *(const bf16x8*)&KT[cur][(n * 16 + lq) * 128 + ((t * 64 + lg * 16) ^ swzk)];
                s = __builtin_amdgcn_mfma_f32_16x16x32_bf16(bk, aq[t], s, 0, 0, 0);
            }
            #pragma unroll
            for (int i = 0; i < 4; ++i) {
                float pe = exp2f(s[i] * SCALE_LOG2E);
                pe = ((pmall >> (n * 4 + i)) & 1u) ? 1.0f : pe;  // masked -> weight 1
                dpart += pe;
                p[n][i] = (bf16)pe;
            }
        }
        // PV: acc[nn] += sum_n P_frag(n) x V_frag(nn,n), all in registers;
        // V B-frag = b64 read: row d = nn*16+lq, k-bytes n*32+lg*8 (^ swz)
        #pragma unroll
        for (int nn = 0; nn < 4; ++nn) {
            #pragma unroll
            for (int n = 0; n < 4; ++n) {
                bf16x4 bv = *(const bf16x4*)&VT[cur][(nn * 16 + lq) * 128 + ((n * 32 + lg * 8) ^ swzk)];
                acc[nn] = pv_mfma(p[n], bv, acc[nn]);
            }
        }
    };
    // counted sync: gl_lds (older) retired, DS pipe drained; 4 mask loads
    // (newest) stay in flight across the barrier.
    auto tile_sync = [&]() {
        asm volatile("s_waitcnt vmcnt(4) lgkmcnt(0)" ::: "memory");
        __builtin_amdgcn_s_barrier();
        __builtin_amdgcn_sched_barrier(0);
    };

    i32x4 raw[4];        // single mask load buffer (freed each tile by extract)

    // prologue: tile 0 -> buf0, mask0 -> raw
    stage(0, 0);
    __builtin_amdgcn_sched_barrier(0);   // keep mask loads newer than gl_lds
    loadmask(0, raw);
    tile_sync();

    int cur = 0;
    for (int kt = 0; kt < NT; ++kt) {
        const bool more = (kt + 1) < NT;                 // wave-uniform
        if (more) stage(kt + 1, cur ^ 1);                // K/V prefetch first
        __builtin_amdgcn_sched_barrier(0);
        // extract raw (tile kt, loaded one tile ago) -> pmall; frees raw
        unsigned pmall = extract(raw);
        if (more) loadmask(kt + 1, raw);                 // next-tile masks, early
        __builtin_amdgcn_sched_barrier(0);
        body(cur, pmall);
        if (more) { tile_sync(); cur ^= 1; }
    }

    // denom: lanes {lq, lq+16, lq+32, lq+48} hold partials for q-row lq
    dpart += __shfl_xor(dpart, 16, 64);
    dpart += __shfl_xor(dpart, 32, 64);
    float dinv = 1.0f / dpart;

    float di[4];
    #pragma unroll
    for (int i = 0; i < 4; ++i) di[i] = __shfl(dinv, lg * 4 + i, 64);

    float* op = out + ((size_t)bh * SLEN + qbase + w * 16) * DH;
    #pragma unroll
    for (int n = 0; n < 4; ++n) {
        #pragma unroll
        for (int i = 0; i < 4; ++i)
            op[(size_t)(lg * 4 + i) * DH + n * 16 + lq] = acc[n][i] * di[i];
    }
}

extern "C" void kernel_launch(void* const* d_in, const int* in_sizes, int n_in,
                              void* d_out, int out_size, void* d_ws, size_t ws_size,
                              hipStream_t stream) {
    const float* Q    = (const float*)d_in[0];
    const float* K    = (const float*)d_in[1];
    const float* V    = (const float*)d_in[2];
    const int*   mask = (const int*)d_in[3];
    float* out = (float*)d_out;

    bf16* Kb  = (bf16*)d_ws;                       // 16 MB
    bf16* Vtb = Kb + (size_t)NBH * SLEN * DH;      // 16 MB

    prep_kv_kernel<<<dim3(SLEN / 64, NBH), 256, 0, stream>>>(K, V, Kb, Vtb);
    attn_kernel<<<2048, 256, 0, stream>>>(Q, mask, Kb, Vtb, out);
}